// Round 8
// baseline (199.759 us; speedup 1.0000x reference)
//
#include <hip/hip_runtime.h>
#include <hip/hip_cooperative_groups.h>
#include <math.h>

namespace cg = cooperative_groups;

// Problem constants
#define BATCH 4
#define NNODE 10000
#define EDIM  32
#define CDIM  128
#define ODIM  128
#define MTOT  (BATCH * NNODE)   // 40000
#define NT_GEMM   1250          // 32-row tiles
#define NT_GATHER 2500          // 16-node tiles

typedef __attribute__((ext_vector_type(8))) short bf16x8;   // MFMA A/B frag (4 VGPRs)
typedef __attribute__((ext_vector_type(4))) float f32x4;    // MFMA C/D frag

// Sentinel bf16 pattern: -2^120; as fp16 bit-interp = -65504 (finite, most
// negative) -> always loses v_pk_max_f16 vs any real T value, never NaN.
#define SENT_BF16 0xFBFFu

__device__ __forceinline__ unsigned short f2bf(float f) {
    unsigned u = __float_as_uint(f);
    u += 0x7fffu + ((u >> 16) & 1u);   // RTNE
    return (unsigned short)(u >> 16);
}
__device__ __forceinline__ float bf2f(unsigned short h) {
    return __uint_as_float(((unsigned)h) << 16);
}
__device__ __forceinline__ void pkmax(unsigned& acc, unsigned v) {
    asm("v_pk_max_f16 %0, %0, %1" : "+v"(acc) : "v"(v));
}

// ---------------------------------------------------------------------------
// prep_w: Bcat[n][k] bf16 ([W1-W2 | W2] transposed) + sentinel T row.
// ---------------------------------------------------------------------------
__global__ __launch_bounds__(256) void prep_w(
    const float* __restrict__ W, unsigned short* __restrict__ Bcat,
    unsigned short* __restrict__ Tsent)
{
    int gid = blockIdx.x * 256 + threadIdx.x;   // 32768 threads
    int n = gid >> 7;          // 0..255
    int k = gid & 127;         // 0..127
    float v;
    if (n < 128) v = W[(size_t)k * ODIM + n] - W[(size_t)(k + 128) * ODIM + n];
    else         v = W[(size_t)(k + 128) * ODIM + (n - 128)];
    Bcat[(size_t)n * CDIM + k] = f2bf(v);
    if (gid < ODIM) Tsent[gid] = (unsigned short)SENT_BF16;
}

// ===========================================================================
// Tile bodies (identical math to R7's kernels), shared by the fused
// cooperative kernel and the non-cooperative fallback kernels.
// ===========================================================================
__device__ __forceinline__ void gemm_tile(
    int t, int tid, unsigned short* As,         // As: 32*128 ushorts LDS
    const float* __restrict__ x, const unsigned short* __restrict__ Bcat,
    const float* __restrict__ bias,
    unsigned short* __restrict__ U, unsigned short* __restrict__ T)
{
    const int m0   = t * 32;
    const int wv   = tid >> 6;
    const int lane = tid & 63;
    const int l16  = lane & 15;
    const int quad = lane >> 4;
    const int nq   = wv * 64;

    // stage + convert: 32 rows x 128 k, coalesced float4 reads
    #pragma unroll
    for (int i = 0; i < 4; i++) {
        int lin = i * 256 + tid;            // float4 index, 0..1023
        int row = lin >> 5;                 // 0..31
        int f4  = lin & 31;
        float4 v = *(const float4*)&x[(size_t)(m0 + row) * CDIM + f4 * 4];
        ushort4 h;
        h.x = f2bf(v.x); h.y = f2bf(v.y); h.z = f2bf(v.z); h.w = f2bf(v.w);
        int kblk = f4 >> 1, half = f4 & 1;
        *(ushort4*)((char*)As + row * 256 + (((kblk ^ (row & 15)) << 4) + half * 8)) = h;
    }
    __syncthreads();

    f32x4 acc[2][4];
    #pragma unroll
    for (int i = 0; i < 2; i++)
        #pragma unroll
        for (int j = 0; j < 4; j++) acc[i][j] = (f32x4){0.f, 0.f, 0.f, 0.f};

    #pragma unroll
    for (int ks = 0; ks < 4; ks++) {
        const int kb = ks * 32 + quad * 8;
        bf16x8 wfr[4];
        #pragma unroll
        for (int ct = 0; ct < 4; ct++)
            wfr[ct] = *(const bf16x8*)(Bcat + (size_t)(nq + ct * 16 + l16) * CDIM + kb);
        bf16x8 xfr[2];
        #pragma unroll
        for (int rt = 0; rt < 2; rt++) {
            int row  = rt * 16 + l16;
            int kblk = ks * 4 + quad;
            xfr[rt] = *(const bf16x8*)((char*)As + row * 256 + ((kblk ^ l16) << 4));
        }
        #pragma unroll
        for (int rt = 0; rt < 2; rt++)
            #pragma unroll
            for (int ct = 0; ct < 4; ct++)
                acc[rt][ct] = __builtin_amdgcn_mfma_f32_16x16x32_bf16(
                    wfr[ct], xfr[rt], acc[rt][ct], 0, 0, 0);
    }

    // epilogue: direct packed stores (D: col=x-row, regs = 4 consecutive cols)
    if (wv < 2) {
        #pragma unroll
        for (int ct = 0; ct < 4; ct++) {
            int c0 = nq + ct * 16 + quad * 4;
            float4 b4 = *(const float4*)&bias[c0];
            #pragma unroll
            for (int rt = 0; rt < 2; rt++) {
                int row = m0 + rt * 16 + l16;
                ushort4 h;
                h.x = f2bf(acc[rt][ct][0] + b4.x);
                h.y = f2bf(acc[rt][ct][1] + b4.y);
                h.z = f2bf(acc[rt][ct][2] + b4.z);
                h.w = f2bf(acc[rt][ct][3] + b4.w);
                *(ushort4*)&U[(size_t)row * ODIM + c0] = h;
            }
        }
    } else {
        #pragma unroll
        for (int ct = 0; ct < 4; ct++) {
            int c0 = (nq - 128) + ct * 16 + quad * 4;
            #pragma unroll
            for (int rt = 0; rt < 2; rt++) {
                int row = m0 + rt * 16 + l16;
                ushort4 h;
                h.x = f2bf(acc[rt][ct][0]);
                h.y = f2bf(acc[rt][ct][1]);
                h.z = f2bf(acc[rt][ct][2]);
                h.w = f2bf(acc[rt][ct][3]);
                *(ushort4*)&T[(size_t)row * ODIM + c0] = h;
            }
        }
    }
}

__device__ __forceinline__ void gather_tile(
    int g, int tid, int (*sidx)[EDIM],          // sidx: 16*32 ints LDS
    const int* __restrict__ idx, const unsigned short* __restrict__ Ub,
    const unsigned short* __restrict__ T, float* __restrict__ out)
{
    const int b   = g & 3;                  // batch (XCD-stable: grid % 8 == 0)
    const int nb0 = (g >> 2) * 16;
    const int sent = NNODE * (BATCH - b);

    #pragma unroll
    for (int i = 0; i < 2; i++) {
        int lin = i * 256 + tid;            // 0..511
        int n = lin >> 5, e = lin & 31;
        int j = idx[(size_t)(b * NNODE + nb0 + n) * EDIM + e];
        sidx[n][e] = (j < 0) ? sent : j;
    }
    __syncthreads();

    const int wv   = tid >> 6;
    const int lane = tid & 63;
    const int q4   = lane >> 4;
    const int l16  = lane & 15;
    const int myn  = wv * 4 + q4;
    const int node = b * NNODE + nb0 + myn;
    const unsigned short* tb = T + (size_t)b * NNODE * ODIM;
    const int o8 = l16 * 8;

    uint4 uraw = *(const uint4*)(Ub + (size_t)node * ODIM + o8);

    const unsigned SENT2 = (SENT_BF16 << 16) | SENT_BF16;
    unsigned m01 = SENT2, m23 = SENT2, m45 = SENT2, m67 = SENT2;

    #pragma unroll
    for (int e0 = 0; e0 < EDIM; e0 += 16) {
        uint4 v[16];
        #pragma unroll
        for (int q = 0; q < 16; q++) {      // 16 gathers in flight
            int j = sidx[myn][e0 + q];
            v[q] = *(const uint4*)(tb + (size_t)j * ODIM + o8);
        }
        #pragma unroll
        for (int q = 0; q < 16; q++) {
            pkmax(m01, v[q].x); pkmax(m23, v[q].y);
            pkmax(m45, v[q].z); pkmax(m67, v[q].w);
        }
    }

    const bool any = (m01 & 0xffffu) != SENT_BF16;
    float m[8];
    m[0] = bf2f((unsigned short)(m01 & 0xffff)); m[1] = bf2f((unsigned short)(m01 >> 16));
    m[2] = bf2f((unsigned short)(m23 & 0xffff)); m[3] = bf2f((unsigned short)(m23 >> 16));
    m[4] = bf2f((unsigned short)(m45 & 0xffff)); m[5] = bf2f((unsigned short)(m45 >> 16));
    m[6] = bf2f((unsigned short)(m67 & 0xffff)); m[7] = bf2f((unsigned short)(m67 >> 16));
    float uu[8];
    uu[0] = bf2f((unsigned short)(uraw.x & 0xffff)); uu[1] = bf2f((unsigned short)(uraw.x >> 16));
    uu[2] = bf2f((unsigned short)(uraw.y & 0xffff)); uu[3] = bf2f((unsigned short)(uraw.y >> 16));
    uu[4] = bf2f((unsigned short)(uraw.z & 0xffff)); uu[5] = bf2f((unsigned short)(uraw.z >> 16));
    uu[6] = bf2f((unsigned short)(uraw.w & 0xffff)); uu[7] = bf2f((unsigned short)(uraw.w >> 16));
    float r[8];
    #pragma unroll
    for (int i = 0; i < 8; i++) {
        float s = uu[i] + m[i];
        r[i] = any ? (s > 0.f ? s : __expf(s) - 1.f) : -INFINITY;
    }
    *(float4*)&out[(size_t)node * ODIM + o8]     = make_float4(r[0], r[1], r[2], r[3]);
    *(float4*)&out[(size_t)node * ODIM + o8 + 4] = make_float4(r[4], r[5], r[6], r[7]);
}

// ---------------------------------------------------------------------------
// Fused cooperative kernel: gemm phase -> grid.sync -> gather phase.
// Grid-stride loops; grid is a multiple of 8 so t%8 stays pinned to one XCD
// (preserves the batch<->XCD L2 locality of the split version). LDS is a
// union of the gemm A-tile (8KB) and the gather index tile (2KB).
// ---------------------------------------------------------------------------
__global__ __launch_bounds__(256, 4) void fused(
    const float* __restrict__ x, const unsigned short* __restrict__ Bcat,
    const float* __restrict__ bias, unsigned short* __restrict__ U,
    unsigned short* __restrict__ T, const int* __restrict__ idx,
    float* __restrict__ out)
{
    __shared__ __align__(16) unsigned short smem[32 * 128];   // 8 KB union
    const int tid = threadIdx.x;

    for (int t = blockIdx.x; t < NT_GEMM; t += gridDim.x) {
        __syncthreads();                    // LDS reuse guard
        gemm_tile(t, tid, smem, x, Bcat, bias, U, T);
    }

    cg::this_grid().sync();

    int (*sidx)[EDIM] = (int(*)[EDIM])smem;
    for (int t = blockIdx.x; t < NT_GATHER; t += gridDim.x) {
        __syncthreads();                    // LDS reuse guard
        gather_tile(t, tid, sidx, idx, U, T, out);
    }
}

// Non-cooperative fallback path (identical math), used if the cooperative
// launch is unavailable; both paths produce bit-identical output.
__global__ __launch_bounds__(256) void gemm_fb(
    const float* __restrict__ x, const unsigned short* __restrict__ Bcat,
    const float* __restrict__ bias, unsigned short* __restrict__ U,
    unsigned short* __restrict__ T)
{
    __shared__ __align__(16) unsigned short smem[32 * 128];
    gemm_tile(blockIdx.x, threadIdx.x, smem, x, Bcat, bias, U, T);
}
__global__ __launch_bounds__(256) void gather_fb(
    const int* __restrict__ idx, const unsigned short* __restrict__ Ub,
    const unsigned short* __restrict__ T, float* __restrict__ out)
{
    __shared__ int sidx[16][EDIM];
    gather_tile(blockIdx.x, threadIdx.x, sidx, idx, Ub, T, out);
}

extern "C" void kernel_launch(void* const* d_in, const int* in_sizes, int n_in,
                              void* d_out, int out_size, void* d_ws, size_t ws_size,
                              hipStream_t stream) {
    const float* x    = (const float*)d_in[0];
    const int*   idx  = (const int*)d_in[1];
    const float* W    = (const float*)d_in[2];
    const float* bias = (const float*)d_in[3];
    float* out        = (float*)d_out;

    // ws layout: T bf16 [(40000+1)*128] | U bf16 [40000*128] | Bcat bf16 [256*128]
    const size_t tBytes = (size_t)(MTOT + 1) * ODIM * sizeof(unsigned short);
    const size_t uBytes = (size_t)MTOT * ODIM * sizeof(unsigned short);
    unsigned short* T    = (unsigned short*)d_ws;
    unsigned short* U    = (unsigned short*)((char*)d_ws + tBytes);
    unsigned short* Bcat = (unsigned short*)((char*)d_ws + tBytes + uBytes);
    unsigned short* Tsent = T + (size_t)MTOT * ODIM;

    prep_w<<<128, 256, 0, stream>>>(W, Bcat, Tsent);

    // Co-residency-safe cooperative grid (deterministic per process).
    int perCU = 0;
    hipError_t qerr = hipOccupancyMaxActiveBlocksPerMultiprocessor(
        &perCU, (const void*)fused, 256, 0);
    int grid = (qerr == hipSuccess && perCU >= 1) ? perCU * 256 : 0;
    if (grid > 1024) grid = 1024;       // multiple of 8 by construction

    hipError_t lerr = hipErrorUnknown;
    if (grid >= 8) {
        void* args[7] = {(void*)&x, (void*)&Bcat, (void*)&bias, (void*)&U,
                         (void*)&T, (void*)&idx, (void*)&out};
        lerr = hipLaunchCooperativeKernel((const void*)fused, dim3(grid),
                                          dim3(256), args, 0, stream);
    }
    if (lerr != hipSuccess) {           // fallback: proven 2-kernel path
        gemm_fb  <<<NT_GEMM,   256, 0, stream>>>(x, Bcat, bias, U, T);
        gather_fb<<<NT_GATHER, 256, 0, stream>>>(idx, U, T, out);
    }
}

// Round 9
// 111.297 us; speedup vs baseline: 1.7948x; 1.7948x over previous
//
#include <hip/hip_runtime.h>
#include <math.h>

// Problem constants
#define BATCH 4
#define NNODE 10000
#define EDIM  32
#define CDIM  128
#define ODIM  128
#define MTOT  (BATCH * NNODE)   // 40000
#define SENTROW MTOT            // absolute sentinel row in T

typedef __attribute__((ext_vector_type(8))) short bf16x8;   // MFMA A/B frag
typedef __attribute__((ext_vector_type(4))) float f32x4;    // MFMA C/D frag

// Sentinel bf16 pattern: -2^120; fp16 bit-interp = -65504 (finite, most
// negative) -> always loses v_pk_max_f16 vs any real T value, never NaN.
#define SENT_BF16 0xFBFFu

__device__ __forceinline__ unsigned short f2bf(float f) {
    unsigned u = __float_as_uint(f);
    u += 0x7fffu + ((u >> 16) & 1u);   // RTNE
    return (unsigned short)(u >> 16);
}
__device__ __forceinline__ float bf2f(unsigned short h) {
    return __uint_as_float(((unsigned)h) << 16);
}
__device__ __forceinline__ void pkmax(unsigned& acc, unsigned v) {
    asm("v_pk_max_f16 %0, %0, %1" : "+v"(acc) : "v"(v));
}

// ---------------------------------------------------------------------------
// prep_w: Bcat[n][k] bf16, n-major. n<128: W1[k][n]-W2[k][n] (U weights);
// n>=128: W2[k][n-128] (T weights). Plus sentinel T row = SENT_BF16.
// ---------------------------------------------------------------------------
__global__ __launch_bounds__(256) void prep_w(
    const float* __restrict__ W, unsigned short* __restrict__ Bcat,
    unsigned short* __restrict__ Tsent)
{
    int gid = blockIdx.x * 256 + threadIdx.x;   // 32768 threads
    int n = gid >> 7;          // 0..255
    int k = gid & 127;         // 0..127
    float v;
    if (n < 128) v = W[(size_t)k * ODIM + n] - W[(size_t)(k + 128) * ODIM + n];
    else         v = W[(size_t)(k + 128) * ODIM + (n - 128)];
    Bcat[(size_t)n * CDIM + k] = f2bf(v);
    if (gid < ODIM) Tsent[gid] = (unsigned short)SENT_BF16;
}

// ---------------------------------------------------------------------------
// Kernel 1: T = x @ W2  (bf16 out). BM=64, 625 blocks, 4 waves x 32 cols.
// Per wave: 4 row-tiles x 2 col-tiles of 16x16x32, K=128. A(x) staged via
// coalesced float4 -> bf16 -> kblk-XOR-swizzled LDS (<=2-way everywhere);
// W2 frags direct 16B loads from L2-hot Bcat (rows 128..255).
// Operand swap (R7-verified): D col(lane&15)=x row, row(quad*4+r)=out col.
// ---------------------------------------------------------------------------
__global__ __launch_bounds__(256) void gemm_t(
    const float* __restrict__ x,            // [40000,128]
    const unsigned short* __restrict__ Bcat,// [256,128] bf16
    unsigned short* __restrict__ T)         // [40001,128] bf16
{
    __shared__ unsigned short As[64 * 128]; // 16KB swizzled [row][k]

    const int tid  = threadIdx.x;
    const int m0   = blockIdx.x * 64;
    const int wv   = tid >> 6;
    const int lane = tid & 63;
    const int l16  = lane & 15;
    const int quad = lane >> 4;
    const int nq   = wv * 32;               // this wave's first out col

    #pragma unroll
    for (int i = 0; i < 8; i++) {
        int lin = i * 256 + tid;            // float4 index, 0..2047
        int row = lin >> 5;                 // 0..63
        int f4  = lin & 31;
        float4 v = *(const float4*)&x[(size_t)(m0 + row) * CDIM + f4 * 4];
        ushort4 h;
        h.x = f2bf(v.x); h.y = f2bf(v.y); h.z = f2bf(v.z); h.w = f2bf(v.w);
        int kblk = f4 >> 1, half = f4 & 1;
        *(ushort4*)((char*)As + row * 256 + (((kblk ^ (row & 15)) << 4) + half * 8)) = h;
    }
    __syncthreads();

    f32x4 acc[4][2];
    #pragma unroll
    for (int i = 0; i < 4; i++)
        #pragma unroll
        for (int j = 0; j < 2; j++) acc[i][j] = (f32x4){0.f, 0.f, 0.f, 0.f};

    #pragma unroll
    for (int ks = 0; ks < 4; ks++) {
        const int kb = ks * 32 + quad * 8;
        bf16x8 wfr[2];
        #pragma unroll
        for (int ct = 0; ct < 2; ct++)      // W2 half of Bcat
            wfr[ct] = *(const bf16x8*)(Bcat + (size_t)(128 + nq + ct * 16 + l16) * CDIM + kb);
        bf16x8 xfr[4];
        #pragma unroll
        for (int rt = 0; rt < 4; rt++) {
            int row  = rt * 16 + l16;
            int kblk = ks * 4 + quad;
            xfr[rt] = *(const bf16x8*)((char*)As + row * 256 + ((kblk ^ l16) << 4));
        }
        #pragma unroll
        for (int rt = 0; rt < 4; rt++)
            #pragma unroll
            for (int ct = 0; ct < 2; ct++)
                acc[rt][ct] = __builtin_amdgcn_mfma_f32_16x16x32_bf16(
                    wfr[ct], xfr[rt], acc[rt][ct], 0, 0, 0);
    }

    #pragma unroll
    for (int ct = 0; ct < 2; ct++) {
        int c0 = nq + ct * 16 + quad * 4;
        #pragma unroll
        for (int rt = 0; rt < 4; rt++) {
            int row = m0 + rt * 16 + l16;
            ushort4 h;
            h.x = f2bf(acc[rt][ct][0]);
            h.y = f2bf(acc[rt][ct][1]);
            h.z = f2bf(acc[rt][ct][2]);
            h.w = f2bf(acc[rt][ct][3]);
            *(ushort4*)&T[(size_t)row * ODIM + c0] = h;
        }
    }
}

// ---------------------------------------------------------------------------
// Kernel 2: fused U-GEMM + gather + elu. Block = 16 nodes (2500 blocks,
// 625/batch -> b = bid&3 keeps the batch<->XCD L2 pinning). Phase 1: U =
// x@(W1-W2)+bias via MFMA (1 row-tile x 2 col-tiles/wave), result straight
// into LDS (fp32, pitch 132 -> U never touches global; also no bf16
// rounding on U anymore). Phase 2: R7's gather (quarter-wave/node, uint4
// bf16x8 loads, sentinel row absolute SENTROW, v_pk_max_f16), U read from
// LDS, elu, float4 stores to out.
// ---------------------------------------------------------------------------
__global__ __launch_bounds__(256) void fused_ug(
    const float* __restrict__ x,            // [40000,128]
    const unsigned short* __restrict__ Bcat,// [256,128] bf16
    const float* __restrict__ bias,         // [128]
    const int* __restrict__ idx,            // [40000,32]
    const unsigned short* __restrict__ T,   // [40001,128] bf16
    float* __restrict__ out)                // [40000,128]
{
    __shared__ unsigned short As[16 * 128]; // 4KB swizzled x tile
    __shared__ float Uf[16 * 132];          // 8.25KB U tile (padded pitch)
    __shared__ int sidx[16][EDIM + 1];      // +1: kills 4-way bank conflict

    const int bid  = blockIdx.x;            // 0..2499
    const int b    = bid & 3;               // batch (XCD-pinned)
    const int nb0  = (bid >> 2) * 16;       // 0..9984
    const int m0   = b * NNODE + nb0;       // global first row
    const int tid  = threadIdx.x;
    const int wv   = tid >> 6;
    const int lane = tid & 63;
    const int l16  = lane & 15;
    const int quad = lane >> 4;
    const int nq   = wv * 32;

    // ---- stage x tile (512 float4) + edge indices (512 ints) ----
    #pragma unroll
    for (int i = 0; i < 2; i++) {
        int lin = i * 256 + tid;            // 0..511
        int row = lin >> 5;                 // 0..15
        int f4  = lin & 31;
        float4 v = *(const float4*)&x[(size_t)(m0 + row) * CDIM + f4 * 4];
        ushort4 h;
        h.x = f2bf(v.x); h.y = f2bf(v.y); h.z = f2bf(v.z); h.w = f2bf(v.w);
        int kblk = f4 >> 1, half = f4 & 1;
        *(ushort4*)((char*)As + row * 256 + (((kblk ^ row) << 4) + half * 8)) = h;
        int j = idx[(size_t)(m0 + row) * EDIM + f4];
        sidx[row][f4] = (j < 0) ? SENTROW : b * NNODE + j;   // absolute row
    }
    __syncthreads();

    // ---- U-GEMM: 16 rows x 128 cols, wave owns 32 cols ----
    f32x4 acc[2];
    acc[0] = (f32x4){0.f, 0.f, 0.f, 0.f};
    acc[1] = (f32x4){0.f, 0.f, 0.f, 0.f};
    #pragma unroll
    for (int ks = 0; ks < 4; ks++) {
        const int kb = ks * 32 + quad * 8;
        bf16x8 wfr[2];
        #pragma unroll
        for (int ct = 0; ct < 2; ct++)      // W1-W2 half of Bcat
            wfr[ct] = *(const bf16x8*)(Bcat + (size_t)(nq + ct * 16 + l16) * CDIM + kb);
        int kblk = ks * 4 + quad;
        bf16x8 xfr = *(const bf16x8*)((char*)As + l16 * 256 + ((kblk ^ l16) << 4));
        #pragma unroll
        for (int ct = 0; ct < 2; ct++)
            acc[ct] = __builtin_amdgcn_mfma_f32_16x16x32_bf16(
                wfr[ct], xfr, acc[ct], 0, 0, 0);
    }
    // epilogue -> LDS (+bias). D: col(l16)=x row, row(quad*4+r)=out col.
    #pragma unroll
    for (int ct = 0; ct < 2; ct++) {
        int c0 = nq + ct * 16 + quad * 4;
        float4 b4 = *(const float4*)&bias[c0];
        *(float4*)&Uf[l16 * 132 + c0] = make_float4(
            acc[ct][0] + b4.x, acc[ct][1] + b4.y,
            acc[ct][2] + b4.z, acc[ct][3] + b4.w);
    }
    __syncthreads();

    // ---- gather + max + elu (quarter-wave per node) ----
    const int myn  = tid >> 4;              // 0..15
    const int hl   = tid & 15;
    const int node = m0 + myn;
    const int o8   = hl * 8;                // bf16 col offset (16B aligned)

    const unsigned SENT2 = (SENT_BF16 << 16) | SENT_BF16;
    unsigned m01 = SENT2, m23 = SENT2, m45 = SENT2, m67 = SENT2;

    #pragma unroll
    for (int e0 = 0; e0 < EDIM; e0 += 16) {
        uint4 v[16];
        #pragma unroll
        for (int q = 0; q < 16; q++) {      // 16 gathers in flight
            int j = sidx[myn][e0 + q];
            v[q] = *(const uint4*)(T + (size_t)j * ODIM + o8);
        }
        #pragma unroll
        for (int q = 0; q < 16; q++) {
            pkmax(m01, v[q].x); pkmax(m23, v[q].y);
            pkmax(m45, v[q].z); pkmax(m67, v[q].w);
        }
    }

    const bool any = (m01 & 0xffffu) != SENT_BF16;
    float m[8];
    m[0] = bf2f((unsigned short)(m01 & 0xffff)); m[1] = bf2f((unsigned short)(m01 >> 16));
    m[2] = bf2f((unsigned short)(m23 & 0xffff)); m[3] = bf2f((unsigned short)(m23 >> 16));
    m[4] = bf2f((unsigned short)(m45 & 0xffff)); m[5] = bf2f((unsigned short)(m45 >> 16));
    m[6] = bf2f((unsigned short)(m67 & 0xffff)); m[7] = bf2f((unsigned short)(m67 >> 16));

    float4 u0 = *(const float4*)&Uf[myn * 132 + o8];
    float4 u1 = *(const float4*)&Uf[myn * 132 + o8 + 4];
    float uu[8] = {u0.x, u0.y, u0.z, u0.w, u1.x, u1.y, u1.z, u1.w};
    float r[8];
    #pragma unroll
    for (int i = 0; i < 8; i++) {
        float s = uu[i] + m[i];
        r[i] = any ? (s > 0.f ? s : __expf(s) - 1.f) : -INFINITY;
    }
    *(float4*)&out[(size_t)node * ODIM + o8]     = make_float4(r[0], r[1], r[2], r[3]);
    *(float4*)&out[(size_t)node * ODIM + o8 + 4] = make_float4(r[4], r[5], r[6], r[7]);
}

extern "C" void kernel_launch(void* const* d_in, const int* in_sizes, int n_in,
                              void* d_out, int out_size, void* d_ws, size_t ws_size,
                              hipStream_t stream) {
    const float* x    = (const float*)d_in[0];
    const int*   idx  = (const int*)d_in[1];
    const float* W    = (const float*)d_in[2];
    const float* bias = (const float*)d_in[3];
    float* out        = (float*)d_out;

    // ws layout: T bf16 [(40000+1)*128] | Bcat bf16 [256*128]  (no U buffer!)
    const size_t tBytes = (size_t)(MTOT + 1) * ODIM * sizeof(unsigned short);
    unsigned short* T     = (unsigned short*)d_ws;
    unsigned short* Bcat  = (unsigned short*)((char*)d_ws + tBytes);
    unsigned short* Tsent = T + (size_t)MTOT * ODIM;

    prep_w  <<<128,       256, 0, stream>>>(W, Bcat, Tsent);
    gemm_t  <<<MTOT / 64, 256, 0, stream>>>(x, Bcat, T);
    fused_ug<<<MTOT / 16, 256, 0, stream>>>(x, Bcat, bias, idx, T, out);
}